// Round 5
// baseline (354.509 us; speedup 1.0000x reference)
//
#include <hip/hip_runtime.h>
#include <hip/hip_bf16.h>

// MHA: B=2, S=2048, D=1024, H=16, HD=64. fp32 in, fp32 out.
// ws (32MB, proven safe):
//   [0,8)MB   Qb bf16 [B,H,S,HD]          (later reused: Wot @[0,2) after fattn)
//   [8,16)MB  Kb bf16 [B,H,S,HD]
//   [16,24)MB Vtb bf16 [B,H,HD,S]
//   [24,32)MB Wqt/Wkt/Wvt bf16 [N][K] (2MB each)  -> reused as ctx bf16 [B,S,D] after QKV GEMMs
// Q-proj scale folds 1/sqrt(HD)*log2(e) so fattn uses native exp2.

typedef short s16x8 __attribute__((ext_vector_type(8)));
typedef float f32x4v __attribute__((ext_vector_type(4)));

__device__ inline unsigned short f2bf(float f) {   // RNE
    union { float f; unsigned int i; } x; x.f = f;
    unsigned int r = x.i + 0x7FFFu + ((x.i >> 16) & 1u);
    return (unsigned short)(r >> 16);
}

// async global->LDS, 16B per lane. ldsptr must be wave-uniform; HW writes base + lane*16.
__device__ inline void gld_lds16(const unsigned short* g, unsigned short* l) {
    __builtin_amdgcn_global_load_lds(
        (const __attribute__((address_space(1))) unsigned int*)(const void*)g,
        (__attribute__((address_space(3))) unsigned int*)(void*)l,
        16, 0, 0);
}

// W[K=1024][N=1024] fp32 -> Wt[N][K] bf16 (transpose+convert). Grid (16,16), 256 thr.
__global__ __launch_bounds__(256)
void cvtW(const float* __restrict__ W, unsigned short* __restrict__ Wt) {
    __shared__ unsigned short Ls[64][68];
    const int t = threadIdx.x;
    const int k0 = blockIdx.y * 64, n0 = blockIdx.x * 64;
    const int r = t >> 4, c4 = (t & 15) * 4;
    #pragma unroll
    for (int i = 0; i < 4; ++i) {
        float4 wv = *(const float4*)&W[(size_t)(k0 + r + i * 16) * 1024 + n0 + c4];
        Ls[c4 + 0][r + i * 16] = f2bf(wv.x);
        Ls[c4 + 1][r + i * 16] = f2bf(wv.y);
        Ls[c4 + 2][r + i * 16] = f2bf(wv.z);
        Ls[c4 + 3][r + i * 16] = f2bf(wv.w);
    }
    __syncthreads();
    #pragma unroll
    for (int i = 0; i < 4; ++i) {
        const int nr = r + i * 16;
        ushort4 u = make_ushort4(Ls[nr][c4], Ls[nr][c4 + 1], Ls[nr][c4 + 2], Ls[nr][c4 + 3]);
        *(ushort4*)&Wt[(size_t)(n0 + nr) * 1024 + k0 + c4] = u;
    }
}

// C[M,N] = A[M,K] @ Wt^T; M=4096, N=K=1024. Wt is [N][K] bf16. 128x128 tile, BK=32,
// global_load_lds staging. LDS layout: 16B blocks p: A [kc][m] (p=kc*128+m), B [kc][n].
// mode 0: bf16 scatter [B,H,S,HD]; mode 2: bf16 scatter [B,H,HD,S]; mode 1: fp32 [M,N].
__global__ __launch_bounds__(256)
void gemm128(const void* __restrict__ Av, const unsigned short* __restrict__ Wt,
             unsigned short* __restrict__ outB, float* __restrict__ outF,
             int aBF, int mode, float scale) {
    __shared__ __align__(16) unsigned short Al[512 * 8];
    __shared__ __align__(16) unsigned short Bl[512 * 8];
    const int t = threadIdx.x;
    const int lane = t & 63, w = t >> 6;
    const int ln = lane & 15, qd = lane >> 4;
    const int mw = (w & 1) * 64, nw = (w >> 1) * 64;
    const int m0 = blockIdx.y * 128, n0 = blockIdx.x * 128;

    f32x4v acc[4][4] = {};

    for (int k0 = 0; k0 < 1024; k0 += 32) {
        __syncthreads();
        #pragma unroll
        for (int i = 0; i < 2; ++i) {   // B: pure DMA
            const int p = i * 256 + t;
            gld_lds16(Wt + (size_t)(n0 + (p & 127)) * 1024 + k0 + (p >> 7) * 8,
                      &Bl[(i * 256 + w * 64) * 8]);
        }
        if (aBF) {
            #pragma unroll
            for (int i = 0; i < 2; ++i) {
                const int p = i * 256 + t;
                gld_lds16((const unsigned short*)Av + (size_t)(m0 + (p & 127)) * 1024 + k0 + (p >> 7) * 8,
                          &Al[(i * 256 + w * 64) * 8]);
            }
        } else {
            #pragma unroll
            for (int i = 0; i < 2; ++i) {
                const int p = i * 256 + t;
                const float* src = (const float*)Av + (size_t)(m0 + (p & 127)) * 1024 + k0 + (p >> 7) * 8;
                float4 f0 = ((const float4*)src)[0];
                float4 f1 = ((const float4*)src)[1];
                s16x8 v;
                v[0] = (short)f2bf(f0.x); v[1] = (short)f2bf(f0.y);
                v[2] = (short)f2bf(f0.z); v[3] = (short)f2bf(f0.w);
                v[4] = (short)f2bf(f1.x); v[5] = (short)f2bf(f1.y);
                v[6] = (short)f2bf(f1.z); v[7] = (short)f2bf(f1.w);
                *(s16x8*)&Al[p * 8] = v;
            }
        }
        __syncthreads();

        s16x8 a[4], b[4];
        #pragma unroll
        for (int mt = 0; mt < 4; ++mt) a[mt] = *(const s16x8*)&Al[(qd * 128 + mw + mt * 16 + ln) * 8];
        #pragma unroll
        for (int nt = 0; nt < 4; ++nt) b[nt] = *(const s16x8*)&Bl[(qd * 128 + nw + nt * 16 + ln) * 8];
        #pragma unroll
        for (int mt = 0; mt < 4; ++mt)
            #pragma unroll
            for (int nt = 0; nt < 4; ++nt)
                acc[mt][nt] = __builtin_amdgcn_mfma_f32_16x16x32_bf16(a[mt], b[nt], acc[mt][nt], 0, 0, 0);
    }

    #pragma unroll
    for (int mt = 0; mt < 4; ++mt)
        #pragma unroll
        for (int nt = 0; nt < 4; ++nt)
            #pragma unroll
            for (int i = 0; i < 4; ++i) {
                const int m = m0 + mw + mt * 16 + qd * 4 + i;  // C/D: row=quad*4+reg
                const int n = n0 + nw + nt * 16 + ln;          // C/D: col=lane&15
                const float v = acc[mt][nt][i] * scale;
                if (mode == 0) {
                    const size_t idx = (((size_t)(m >> 11) * 16 + (n >> 6)) * 2048 + (m & 2047)) * 64 + (n & 63);
                    outB[idx] = f2bf(v);
                } else if (mode == 2) {
                    const size_t idx = ((((size_t)(m >> 11) * 16 + (n >> 6)) * 64 + (n & 63)) * 2048) + (m & 2047);
                    outB[idx] = f2bf(v);
                } else {
                    outF[(size_t)m * 1024 + n] = v;
                }
            }
}

// Flash attention. Grid (16, 32) = (S/128 q-tiles, B*H). 512 thr = 8 waves x 16 q-rows.
// Q,K bf16 [B,H,S,HD]; Vt bf16 [B,H,HD,S]; ctx bf16 [B,S,D]. No max-subtraction
// (logits ~N(0,1), exp2 cannot overflow fp32; exact-math identical to softmax).
// LDS: Ks2/Vs2 16B blocks [chunk][row]; staging wave w loads chunk w via global_load_lds.
__global__ __launch_bounds__(512)
void fattn(const unsigned short* __restrict__ Q, const unsigned short* __restrict__ K,
           const unsigned short* __restrict__ Vt, unsigned short* __restrict__ ctx) {
    __shared__ __align__(16) unsigned short Ks2[512 * 8];   // p=kc*64+key: K[key][kc*8..+8]
    __shared__ __align__(16) unsigned short Vs2[512 * 8];   // p=kc*64+d:  Vt[d][kt*64+kc*8..+8]
    __shared__ __align__(16) unsigned short Pw[8][16 * 72]; // per-wave P [m][key]

    const int t = threadIdx.x, lane = t & 63, w = t >> 6;
    const int ln = lane & 15, qd = lane >> 4;
    const int bh = blockIdx.y, m0 = blockIdx.x * 128;
    const size_t head = (size_t)bh * 2048 * 64;
    const unsigned short* Kg = K + head;
    const unsigned short* Vg = Vt + head;

    s16x8 qf[2];
    #pragma unroll
    for (int kk = 0; kk < 2; ++kk)
        qf[kk] = *(const s16x8*)(Q + head + (size_t)(m0 + w * 16 + ln) * 64 + kk * 32 + qd * 8);

    f32x4v accO[4] = {};
    float lsum[4] = {};
    unsigned short* pw = Pw[w];

    for (int kt = 0; kt < 32; ++kt) {
        __syncthreads();
        gld_lds16(Kg + (size_t)(kt * 64 + lane) * 64 + w * 8, &Ks2[(w * 64) * 8]);
        gld_lds16(Vg + (size_t)lane * 2048 + kt * 64 + w * 8, &Vs2[(w * 64) * 8]);
        __syncthreads();

        // S = Q K^T (pre-scaled by log2e)
        f32x4v accS[4] = {};
        #pragma unroll
        for (int kk = 0; kk < 2; ++kk)
            #pragma unroll
            for (int nt = 0; nt < 4; ++nt) {
                s16x8 b = *(const s16x8*)&Ks2[((kk * 4 + qd) * 64 + nt * 16 + ln) * 8];
                accS[nt] = __builtin_amdgcn_mfma_f32_16x16x32_bf16(qf[kk], b, accS[nt], 0, 0, 0);
            }

        // P = 2^S, row-sums, spill to per-wave LDS (C-layout -> A-layout)
        #pragma unroll
        for (int nt = 0; nt < 4; ++nt)
            #pragma unroll
            for (int i = 0; i < 4; ++i) {
                float p = exp2f(accS[nt][i]);
                lsum[i] += p;
                pw[(qd * 4 + i) * 72 + nt * 16 + ln] = f2bf(p);
            }

        // O += P V
        #pragma unroll
        for (int kk = 0; kk < 2; ++kk) {
            s16x8 a = *(const s16x8*)&pw[ln * 72 + kk * 32 + qd * 8];
            #pragma unroll
            for (int nt = 0; nt < 4; ++nt) {
                s16x8 b = *(const s16x8*)&Vs2[((kk * 4 + qd) * 64 + nt * 16 + ln) * 8];
                accO[nt] = __builtin_amdgcn_mfma_f32_16x16x32_bf16(a, b, accO[nt], 0, 0, 0);
            }
        }
    }

    #pragma unroll
    for (int i = 0; i < 4; ++i) {
        float s = lsum[i];
        #pragma unroll
        for (int off = 1; off < 16; off <<= 1) s += __shfl_xor(s, off, 64);
        lsum[i] = 1.f / s;
    }

    const int b = bh >> 4, hh = bh & 15;
    #pragma unroll
    for (int i = 0; i < 4; ++i) {
        const int srow = m0 + w * 16 + qd * 4 + i;
        #pragma unroll
        for (int nt = 0; nt < 4; ++nt)
            ctx[(((size_t)b * 2048 + srow) * 16 + hh) * 64 + nt * 16 + ln] = f2bf(accO[nt][i] * lsum[i]);
    }
}

extern "C" void kernel_launch(void* const* d_in, const int* in_sizes, int n_in,
                              void* d_out, int out_size, void* d_ws, size_t ws_size,
                              hipStream_t stream) {
    char* ws = (char*)d_ws;
    unsigned short* Qb  = (unsigned short*)(ws);
    unsigned short* Kb  = (unsigned short*)(ws + ((size_t)8 << 20));
    unsigned short* Vtb = (unsigned short*)(ws + ((size_t)16 << 20));
    unsigned short* Wqt = (unsigned short*)(ws + ((size_t)24 << 20));
    unsigned short* Wkt = (unsigned short*)(ws + ((size_t)26 << 20));
    unsigned short* Wvt = (unsigned short*)(ws + ((size_t)28 << 20));
    unsigned short* ctx = (unsigned short*)(ws + ((size_t)24 << 20));  // overlays dead Wq/Wk/Wv t
    unsigned short* Wot = (unsigned short*)(ws);                        // overlays dead Qb

    cvtW<<<dim3(16, 16), 256, 0, stream>>>((const float*)d_in[3], Wqt);
    cvtW<<<dim3(16, 16), 256, 0, stream>>>((const float*)d_in[4], Wkt);
    cvtW<<<dim3(16, 16), 256, 0, stream>>>((const float*)d_in[5], Wvt);

    dim3 gg(8, 32), bb(256);
    gemm128<<<gg, bb, 0, stream>>>(d_in[0], Wqt, Qb, nullptr, 0, 0, 0.125f * 1.44269504f);
    gemm128<<<gg, bb, 0, stream>>>(d_in[1], Wkt, Kb, nullptr, 0, 0, 1.0f);
    gemm128<<<gg, bb, 0, stream>>>(d_in[2], Wvt, Vtb, nullptr, 0, 2, 1.0f);

    fattn<<<dim3(16, 32), dim3(512), 0, stream>>>(Qb, Kb, Vtb, ctx);

    cvtW<<<dim3(16, 16), 256, 0, stream>>>((const float*)d_in[6], Wot);
    gemm128<<<gg, bb, 0, stream>>>(ctx, Wot, nullptr, (float*)d_out, 1, 1, 1.0f);
}

// Round 6
// 300.111 us; speedup vs baseline: 1.1813x; 1.1813x over previous
//
#include <hip/hip_runtime.h>
#include <hip/hip_bf16.h>

// MHA: B=2, S=2048, D=1024, H=16, HD=64. fp32 in, fp32 out.
// All inter-kernel tensors are bf16 in 16B-block swizzled layouts so every
// consumer stages with CONTIGUOUS global_load_lds (lane order = LDS order).
//   A/W swizzle (GEMM operand [R rows][K=1024]): block g=((r>>7)*128+(k>>3))*128+(r&127)
//   K_sw/V_sw (fattn): block g=((bh*32+kt)*8+kc)*64+row  (kc: 8-elem chunk, row: key or hd)
// ws: [0,8)MB Qb [B,H,S,HD] | [8,16) K_sw | [16,24) V_sw | [24,32) Wqt/Wkt/Wvt (2MB each)
//     ctx_sw overlays [24,32) after QKV GEMMs; Wot overlays [0,2) after fattn.
// Q-proj scale folds 1/sqrt(HD)*log2(e) so fattn uses native exp2.

typedef short s16x8 __attribute__((ext_vector_type(8)));
typedef float f32x4v __attribute__((ext_vector_type(4)));

__device__ inline unsigned short f2bf(float f) {   // RNE
    union { float f; unsigned int i; } x; x.f = f;
    unsigned int r = x.i + 0x7FFFu + ((x.i >> 16) & 1u);
    return (unsigned short)(r >> 16);
}

// async global->LDS, 16B/lane. LDS base wave-uniform; HW writes base + lane*16.
__device__ inline void gld_lds16(const unsigned short* g, unsigned short* l) {
    __builtin_amdgcn_global_load_lds(
        (const __attribute__((address_space(1))) unsigned int*)(const void*)g,
        (__attribute__((address_space(3))) unsigned int*)(void*)l,
        16, 0, 0);
}

// W[K=1024][N=1024] fp32 -> Wt bf16 in A/W swizzle (transpose+convert). Grid (16,16).
__global__ __launch_bounds__(256)
void cvtW(const float* __restrict__ W, unsigned short* __restrict__ Wt) {
    __shared__ __align__(16) unsigned short Ls[64 * 72];  // [n][k], stride 72 (16B-aligned rows)
    const int t = threadIdx.x;
    const int k0 = blockIdx.y * 64, n0 = blockIdx.x * 64;
    const int r = t >> 4, c4 = (t & 15) * 4;
    #pragma unroll
    for (int i = 0; i < 4; ++i) {
        float4 wv = *(const float4*)&W[(size_t)(k0 + r + i * 16) * 1024 + n0 + c4];
        Ls[(c4 + 0) * 72 + r + i * 16] = f2bf(wv.x);
        Ls[(c4 + 1) * 72 + r + i * 16] = f2bf(wv.y);
        Ls[(c4 + 2) * 72 + r + i * 16] = f2bf(wv.z);
        Ls[(c4 + 3) * 72 + r + i * 16] = f2bf(wv.w);
    }
    __syncthreads();
    #pragma unroll
    for (int i = 0; i < 2; ++i) {
        const int p = i * 256 + t;
        const int n = p & 63, kc = p >> 6;              // kc 0..7
        s16x8 v = *(const s16x8*)&Ls[n * 72 + kc * 8];
        const int gn = n0 + n, k = k0 + kc * 8;
        const size_t g = ((size_t)(gn >> 7) * 128 + (k >> 3)) * 128 + (gn & 127);
        *(s16x8*)&Wt[g * 8] = v;                        // contiguous 1KB per wave-instr
    }
}

// C[M=4096,N=1024] = A @ W^T, K=1024. 128x128 tile, BK=64, contiguous DMA staging.
// aBF=1: A bf16 in A/W swizzle (DMA). aBF=0: A fp32 row-major [M][1024], converted
// in-register, LDS blocks XOR-swizzled kc*128+(row^kc) (conflict-free write+read).
// mode 0: Q scatter [B,H,S,HD]; mode 3: K_sw; mode 4: V_sw; mode 1: fp32 [M][N].
__global__ __launch_bounds__(256)
void gemm128(const void* __restrict__ Av, const unsigned short* __restrict__ Bsw,
             unsigned short* __restrict__ outB, float* __restrict__ outF,
             int aBF, int mode, float scale) {
    __shared__ __align__(16) unsigned short Al[1024 * 8];   // 16KB: [kc8][row128] blocks
    __shared__ __align__(16) unsigned short Bl[1024 * 8];
    const int t = threadIdx.x;
    const int lane = t & 63, w = t >> 6;
    const int ln = lane & 15, qd = lane >> 4;
    const int mw = (w & 1) * 64, nw = (w >> 1) * 64;
    const int m0 = blockIdx.y * 128, n0 = blockIdx.x * 128;

    f32x4v acc[4][4] = {};

    for (int k0 = 0; k0 < 1024; k0 += 64) {
        __syncthreads();
        {   // B: contiguous DMA (1024 blocks)
            const size_t gb = ((size_t)(n0 >> 7) * 128 + (k0 >> 3)) * 128;
            #pragma unroll
            for (int j = 0; j < 4; ++j)
                gld_lds16(Bsw + (gb + j * 256 + t) * 8, &Bl[(j * 256 + w * 64) * 8]);
        }
        if (aBF) {
            const size_t ga = ((size_t)(m0 >> 7) * 128 + (k0 >> 3)) * 128;
            #pragma unroll
            for (int j = 0; j < 4; ++j)
                gld_lds16((const unsigned short*)Av + (ga + j * 256 + t) * 8,
                          &Al[(j * 256 + w * 64) * 8]);
        } else {
            #pragma unroll
            for (int j = 0; j < 4; ++j) {
                const int p = j * 256 + t;
                const int row = p >> 3, kc = p & 7;     // 8 lanes cover one row's 256B
                const float* src = (const float*)Av + (size_t)(m0 + row) * 1024 + k0 + kc * 8;
                float4 f0 = ((const float4*)src)[0];
                float4 f1 = ((const float4*)src)[1];
                s16x8 v;
                v[0] = (short)f2bf(f0.x); v[1] = (short)f2bf(f0.y);
                v[2] = (short)f2bf(f0.z); v[3] = (short)f2bf(f0.w);
                v[4] = (short)f2bf(f1.x); v[5] = (short)f2bf(f1.y);
                v[6] = (short)f2bf(f1.z); v[7] = (short)f2bf(f1.w);
                *(s16x8*)&Al[(kc * 128 + (row ^ kc)) * 8] = v;
            }
        }
        __syncthreads();

        #pragma unroll
        for (int kk = 0; kk < 2; ++kk) {
            const int kc = kk * 4 + qd;
            const int ax = aBF ? 0 : kc;
            s16x8 a[4], b[4];
            #pragma unroll
            for (int mt = 0; mt < 4; ++mt)
                a[mt] = *(const s16x8*)&Al[(kc * 128 + ((mw + mt * 16 + ln) ^ ax)) * 8];
            #pragma unroll
            for (int nt = 0; nt < 4; ++nt)
                b[nt] = *(const s16x8*)&Bl[(kc * 128 + nw + nt * 16 + ln) * 8];
            #pragma unroll
            for (int mt = 0; mt < 4; ++mt)
                #pragma unroll
                for (int nt = 0; nt < 4; ++nt)
                    acc[mt][nt] = __builtin_amdgcn_mfma_f32_16x16x32_bf16(a[mt], b[nt], acc[mt][nt], 0, 0, 0);
        }
    }

    #pragma unroll
    for (int mt = 0; mt < 4; ++mt)
        #pragma unroll
        for (int nt = 0; nt < 4; ++nt)
            #pragma unroll
            for (int i = 0; i < 4; ++i) {
                const int m = m0 + mw + mt * 16 + qd * 4 + i;  // C/D: row=quad*4+reg
                const int n = n0 + nw + nt * 16 + ln;          // C/D: col=lane&15
                const float v = acc[mt][nt][i] * scale;
                if (mode == 0) {            // Q: [B,H,S,HD]
                    const int bh = (m >> 11) * 16 + (n >> 6), s = m & 2047;
                    outB[((size_t)bh * 2048 + s) * 64 + (n & 63)] = f2bf(v);
                } else if (mode == 3) {     // K_sw
                    const int bh = (m >> 11) * 16 + (n >> 6), s = m & 2047, hd = n & 63;
                    const size_t g = ((size_t)(bh * 32 + (s >> 6)) * 8 + (hd >> 3)) * 64 + (s & 63);
                    outB[g * 8 + (hd & 7)] = f2bf(v);
                } else if (mode == 4) {     // V_sw
                    const int bh = (m >> 11) * 16 + (n >> 6), s = m & 2047, hd = n & 63;
                    const size_t g = ((size_t)(bh * 32 + (s >> 6)) * 8 + ((s >> 3) & 7)) * 64 + hd;
                    outB[g * 8 + (s & 7)] = f2bf(v);
                } else {                    // fp32 out
                    outF[(size_t)m * 1024 + n] = v;
                }
            }
}

// Flash attention. Grid (16,32) = (S/128, B*H). 512 thr = 8 waves x 16 q-rows.
// Q [B,H,S,HD]; K_sw/V_sw swizzled; ctx written in A/W swizzle for the final GEMM.
// No max-subtraction (logits ~N(0,1); exp2 cannot overflow fp32).
__global__ __launch_bounds__(512)
void fattn(const unsigned short* __restrict__ Q, const unsigned short* __restrict__ Ksw,
           const unsigned short* __restrict__ Vsw, unsigned short* __restrict__ ctx) {
    __shared__ __align__(16) unsigned short Ks2[512 * 8];   // [kc8][key64]
    __shared__ __align__(16) unsigned short Vs2[512 * 8];   // [kc8][d64]
    __shared__ __align__(16) unsigned short Pw[8][16 * 72]; // per-wave P [m][key]

    const int t = threadIdx.x, lane = t & 63, w = t >> 6;
    const int ln = lane & 15, qd = lane >> 4;
    const int bh = blockIdx.y, m0 = blockIdx.x * 128;
    const size_t head = (size_t)bh * 2048 * 64;

    s16x8 qf[2];
    #pragma unroll
    for (int kk = 0; kk < 2; ++kk)
        qf[kk] = *(const s16x8*)(Q + head + (size_t)(m0 + w * 16 + ln) * 64 + kk * 32 + qd * 8);

    f32x4v accO[4] = {};
    float lsum[4] = {};
    unsigned short* pw = Pw[w];

    for (int kt = 0; kt < 32; ++kt) {
        __syncthreads();
        const size_t tb = ((size_t)bh * 32 + kt) * 512;   // 512 blocks per (bh,kt)
        gld_lds16(Ksw + (tb + w * 64 + lane) * 8, &Ks2[(w * 64) * 8]);   // contiguous 1KB/wave
        gld_lds16(Vsw + (tb + w * 64 + lane) * 8, &Vs2[(w * 64) * 8]);
        __syncthreads();

        // S = Q K^T (pre-scaled by log2e)
        f32x4v accS[4] = {};
        #pragma unroll
        for (int kk = 0; kk < 2; ++kk)
            #pragma unroll
            for (int nt = 0; nt < 4; ++nt) {
                s16x8 b = *(const s16x8*)&Ks2[((kk * 4 + qd) * 64 + nt * 16 + ln) * 8];
                accS[nt] = __builtin_amdgcn_mfma_f32_16x16x32_bf16(qf[kk], b, accS[nt], 0, 0, 0);
            }

        // P = 2^S, row-sums, spill to per-wave LDS (C-layout -> A-layout)
        #pragma unroll
        for (int nt = 0; nt < 4; ++nt)
            #pragma unroll
            for (int i = 0; i < 4; ++i) {
                float p = exp2f(accS[nt][i]);
                lsum[i] += p;
                pw[(qd * 4 + i) * 72 + nt * 16 + ln] = f2bf(p);
            }

        // O += P V
        #pragma unroll
        for (int kk = 0; kk < 2; ++kk) {
            s16x8 a = *(const s16x8*)&pw[ln * 72 + kk * 32 + qd * 8];
            #pragma unroll
            for (int nt = 0; nt < 4; ++nt) {
                s16x8 b = *(const s16x8*)&Vs2[((kk * 4 + qd) * 64 + nt * 16 + ln) * 8];
                accO[nt] = __builtin_amdgcn_mfma_f32_16x16x32_bf16(a, b, accO[nt], 0, 0, 0);
            }
        }
    }

    #pragma unroll
    for (int i = 0; i < 4; ++i) {
        float s = lsum[i];
        #pragma unroll
        for (int off = 1; off < 16; off <<= 1) s += __shfl_xor(s, off, 64);
        lsum[i] = 1.f / s;
    }

    // ctx in A/W swizzle: m = b*2048+s (row of [4096][1024] A), k = h*64+d
    #pragma unroll
    for (int i = 0; i < 4; ++i) {
        const int mrow = (bh >> 4) * 2048 + m0 + w * 16 + qd * 4 + i;
        #pragma unroll
        for (int nt = 0; nt < 4; ++nt) {
            const int k = (bh & 15) * 64 + nt * 16 + ln;
            const size_t g = ((size_t)(mrow >> 7) * 128 + (k >> 3)) * 128 + (mrow & 127);
            ctx[g * 8 + (k & 7)] = f2bf(accO[nt][i] * lsum[i]);
        }
    }
}

extern "C" void kernel_launch(void* const* d_in, const int* in_sizes, int n_in,
                              void* d_out, int out_size, void* d_ws, size_t ws_size,
                              hipStream_t stream) {
    char* ws = (char*)d_ws;
    unsigned short* Qb  = (unsigned short*)(ws);
    unsigned short* Ksw = (unsigned short*)(ws + ((size_t)8 << 20));
    unsigned short* Vsw = (unsigned short*)(ws + ((size_t)16 << 20));
    unsigned short* Wqt = (unsigned short*)(ws + ((size_t)24 << 20));
    unsigned short* Wkt = (unsigned short*)(ws + ((size_t)26 << 20));
    unsigned short* Wvt = (unsigned short*)(ws + ((size_t)28 << 20));
    unsigned short* ctx = (unsigned short*)(ws + ((size_t)24 << 20));  // after QKV GEMMs
    unsigned short* Wot = (unsigned short*)(ws);                        // after fattn (Qb dead)

    cvtW<<<dim3(16, 16), 256, 0, stream>>>((const float*)d_in[3], Wqt);
    cvtW<<<dim3(16, 16), 256, 0, stream>>>((const float*)d_in[4], Wkt);
    cvtW<<<dim3(16, 16), 256, 0, stream>>>((const float*)d_in[5], Wvt);

    dim3 gg(8, 32), bb(256);
    gemm128<<<gg, bb, 0, stream>>>(d_in[0], Wqt, Qb, nullptr, 0, 0, 0.125f * 1.44269504f);
    gemm128<<<gg, bb, 0, stream>>>(d_in[1], Wkt, Ksw, nullptr, 0, 3, 1.0f);
    gemm128<<<gg, bb, 0, stream>>>(d_in[2], Wvt, Vsw, nullptr, 0, 4, 1.0f);

    fattn<<<dim3(16, 32), dim3(512), 0, stream>>>(Qb, Ksw, Vsw, ctx);

    cvtW<<<dim3(16, 16), 256, 0, stream>>>((const float*)d_in[6], Wot);
    gemm128<<<gg, bb, 0, stream>>>(ctx, Wot, nullptr, (float*)d_out, 1, 1, 1.0f);
}

// Round 9
// 244.822 us; speedup vs baseline: 1.4480x; 1.2258x over previous
//
#include <hip/hip_runtime.h>
#include <hip/hip_bf16.h>

// MHA: B=2, S=2048, D=1024, H=16, HD=64. fp32 in, fp32 out.
// Swizzled bf16 inter-kernel layouts (16B blocks) so all staging is contiguous DMA:
//   A/W swizzle ([R][K=1024]): block g=((r>>7)*128+(k>>3))*128+(r&127)
//   K_sw/V_sw: block g=((bh*32+kt)*8+kc)*64+row
// ws: [0,8)MB Qb [B,H,S,HD] | [8,16) K_sw | [16,24) V_sw | [24,32) Wqt/Wkt/Wvt (2MB each)
//     ctx_sw overlays [24,32) after QKV GEMM; Wot overlays [0,2) after fattn.
// Q-proj scale folds 1/sqrt(HD)*log2(e) so fattn uses native exp2.
// R8 post-mortem: gemm_out's B-staging passed a WAVE-UNIFORM global address to
// global_load_lds (all lanes fetched the same 16B). Global address must be per-lane.

typedef short s16x8 __attribute__((ext_vector_type(8)));
typedef float f32x4v __attribute__((ext_vector_type(4)));

__device__ inline unsigned short f2bf(float f) {   // RNE (proven R2-R6)
    union { float f; unsigned int i; } x; x.f = f;
    unsigned int r = x.i + 0x7FFFu + ((x.i >> 16) & 1u);
    return (unsigned short)(r >> 16);
}
__device__ inline unsigned int pkbf(float lo, float hi) {  // lo16=bf(lo), hi16=bf(hi)
    return (unsigned int)f2bf(lo) | ((unsigned int)f2bf(hi) << 16);
}

// async global->LDS, 16B/lane. Global address PER-LANE; LDS base wave-uniform,
// HW writes base + lane*16.
__device__ inline void gld_lds16(const unsigned short* g, unsigned short* l) {
    __builtin_amdgcn_global_load_lds(
        (const __attribute__((address_space(1))) unsigned int*)(const void*)g,
        (__attribute__((address_space(3))) unsigned int*)(void*)l,
        16, 0, 0);
}

// W[K=1024][N=1024] fp32 -> Wt bf16 in A/W swizzle (transpose+convert). z selects tensor.
__global__ __launch_bounds__(256)
void cvt3(const float* __restrict__ W0, const float* __restrict__ W1, const float* __restrict__ W2,
          unsigned short* __restrict__ T0, unsigned short* __restrict__ T1, unsigned short* __restrict__ T2) {
    const float* W = (blockIdx.z == 0) ? W0 : (blockIdx.z == 1) ? W1 : W2;
    unsigned short* Wt = (blockIdx.z == 0) ? T0 : (blockIdx.z == 1) ? T1 : T2;
    __shared__ __align__(16) unsigned short Ls[64 * 72];
    const int t = threadIdx.x;
    const int k0 = blockIdx.y * 64, n0 = blockIdx.x * 64;
    const int r = t >> 4, c4 = (t & 15) * 4;
    #pragma unroll
    for (int i = 0; i < 4; ++i) {
        float4 wv = *(const float4*)&W[(size_t)(k0 + r + i * 16) * 1024 + n0 + c4];
        Ls[(c4 + 0) * 72 + r + i * 16] = f2bf(wv.x);
        Ls[(c4 + 1) * 72 + r + i * 16] = f2bf(wv.y);
        Ls[(c4 + 2) * 72 + r + i * 16] = f2bf(wv.z);
        Ls[(c4 + 3) * 72 + r + i * 16] = f2bf(wv.w);
    }
    __syncthreads();
    #pragma unroll
    for (int i = 0; i < 2; ++i) {
        const int p = i * 256 + t;
        const int n = p & 63, kc = p >> 6;
        s16x8 v = *(const s16x8*)&Ls[n * 72 + kc * 8];
        const int gn = n0 + n, k = k0 + kc * 8;
        const size_t g = ((size_t)(gn >> 7) * 128 + (k >> 3)) * 128 + (gn & 127);
        *(s16x8*)&Wt[g * 8] = v;
    }
}

// Fused QKV GEMM: C = X @ W^T per z in {Q,K,V}. 128x128 tile, BK=64.
// A fp32 row-major (in-register explicit pack, XOR-swizzled LDS); B via DMA.
// Grid (8, 32, 3) = 768 blocks -> 3 blocks/CU.
__global__ __launch_bounds__(256, 3)
void gemm_qkv(const float* __restrict__ A0, const float* __restrict__ A1, const float* __restrict__ A2,
              const unsigned short* __restrict__ W0, const unsigned short* __restrict__ W1,
              const unsigned short* __restrict__ W2,
              unsigned short* __restrict__ OQ, unsigned short* __restrict__ OK,
              unsigned short* __restrict__ OV, float scaleQ) {
    const int z = blockIdx.z;
    const float* Av = (z == 0) ? A0 : (z == 1) ? A1 : A2;
    const unsigned short* Bsw = (z == 0) ? W0 : (z == 1) ? W1 : W2;
    const float scale = (z == 0) ? scaleQ : 1.0f;

    __shared__ __align__(16) unsigned short Al[1024 * 8];
    __shared__ __align__(16) unsigned short Bl[1024 * 8];
    const int t = threadIdx.x;
    const int lane = t & 63, w = t >> 6;
    const int ln = lane & 15, qd = lane >> 4;
    const int mw = (w & 1) * 64, nw = (w >> 1) * 64;
    const int m0 = blockIdx.y * 128, n0 = blockIdx.x * 128;

    f32x4v acc[4][4] = {};

    for (int k0 = 0; k0 < 1024; k0 += 64) {
        __syncthreads();
        {   // B: contiguous DMA (per-lane address via t)
            const size_t gb = ((size_t)(n0 >> 7) * 128 + (k0 >> 3)) * 128;
            #pragma unroll
            for (int j = 0; j < 4; ++j)
                gld_lds16(Bsw + (gb + j * 256 + t) * 8, &Bl[(j * 256 + w * 64) * 8]);
        }
        #pragma unroll
        for (int j = 0; j < 4; ++j) {       // A: fp32 -> bf16, explicit pack
            const int p = j * 256 + t;
            const int row = p >> 3, kc = p & 7;
            const float* src = Av + (size_t)(m0 + row) * 1024 + k0 + kc * 8;
            float4 f0 = ((const float4*)src)[0];
            float4 f1 = ((const float4*)src)[1];
            uint4 u;
            u.x = pkbf(f0.x, f0.y); u.y = pkbf(f0.z, f0.w);
            u.z = pkbf(f1.x, f1.y); u.w = pkbf(f1.z, f1.w);
            *(uint4*)&Al[(kc * 128 + (row ^ kc)) * 8] = u;
        }
        __syncthreads();

        #pragma unroll
        for (int kk = 0; kk < 2; ++kk) {
            const int kc = kk * 4 + qd;
            s16x8 a[4], b[4];
            #pragma unroll
            for (int mt = 0; mt < 4; ++mt)
                a[mt] = *(const s16x8*)&Al[(kc * 128 + ((mw + mt * 16 + ln) ^ kc)) * 8];
            #pragma unroll
            for (int nt = 0; nt < 4; ++nt)
                b[nt] = *(const s16x8*)&Bl[(kc * 128 + nw + nt * 16 + ln) * 8];
            #pragma unroll
            for (int mt = 0; mt < 4; ++mt)
                #pragma unroll
                for (int nt = 0; nt < 4; ++nt)
                    acc[mt][nt] = __builtin_amdgcn_mfma_f32_16x16x32_bf16(a[mt], b[nt], acc[mt][nt], 0, 0, 0);
        }
    }

    #pragma unroll
    for (int mt = 0; mt < 4; ++mt)
        #pragma unroll
        for (int nt = 0; nt < 4; ++nt)
            #pragma unroll
            for (int i = 0; i < 4; ++i) {
                const int m = m0 + mw + mt * 16 + qd * 4 + i;
                const int n = n0 + nw + nt * 16 + ln;
                const float v = acc[mt][nt][i] * scale;
                const int bh = (m >> 11) * 16 + (n >> 6), s = m & 2047, hd = n & 63;
                if (z == 0) {
                    OQ[((size_t)bh * 2048 + s) * 64 + hd] = f2bf(v);
                } else if (z == 1) {
                    const size_t g = ((size_t)(bh * 32 + (s >> 6)) * 8 + (hd >> 3)) * 64 + (s & 63);
                    OK[g * 8 + (hd & 7)] = f2bf(v);
                } else {
                    const size_t g = ((size_t)(bh * 32 + (s >> 6)) * 8 + ((s >> 3) & 7)) * 64 + hd;
                    OV[g * 8 + (s & 7)] = f2bf(v);
                }
            }
}

// Output GEMM: out[M=4096][N=1024] fp32 = ctx_sw @ Wot^T. 128x64 tile, BK=64.
// Grid (16, 32) = 512 blocks -> 2 blocks/CU. Wave tile 64x32.
__global__ __launch_bounds__(256, 2)
void gemm_out(const unsigned short* __restrict__ Asw, const unsigned short* __restrict__ Bsw,
              float* __restrict__ outF) {
    __shared__ __align__(16) unsigned short Al[1024 * 8];
    __shared__ __align__(16) unsigned short Bl[512 * 8];
    const int t = threadIdx.x;
    const int lane = t & 63, w = t >> 6;
    const int ln = lane & 15, qd = lane >> 4;
    const int mw = (w & 1) * 64, nw = (w >> 1) * 32;
    const int m0 = blockIdx.y * 128, n0 = blockIdx.x * 64;

    f32x4v acc[4][2] = {};

    for (int k0 = 0; k0 < 1024; k0 += 64) {
        __syncthreads();
        {   // A: 1024 contiguous blocks (per-lane address via t)
            const size_t ga = ((size_t)(m0 >> 7) * 128 + (k0 >> 3)) * 128;
            #pragma unroll
            for (int j = 0; j < 4; ++j)
                gld_lds16(Asw + (ga + j * 256 + t) * 8, &Al[(j * 256 + w * 64) * 8]);
        }
        {   // B: 8 chunks of 64 contiguous blocks; wave w takes chunks 2w, 2w+1.
            // R8 BUG FIX: global address must be PER-LANE (+ lane).
            #pragma unroll
            for (int i = 0; i < 2; ++i) {
                const int c = w * 2 + i;
                const size_t gb = ((size_t)(n0 >> 7) * 128 + (k0 >> 3) + c) * 128 + (n0 & 127) + lane;
                gld_lds16(Bsw + gb * 8, &Bl[(c * 64) * 8]);
            }
        }
        __syncthreads();

        #pragma unroll
        for (int kk = 0; kk < 2; ++kk) {
            const int kc = kk * 4 + qd;
            s16x8 a[4], b[2];
            #pragma unroll
            for (int mt = 0; mt < 4; ++mt)
                a[mt] = *(const s16x8*)&Al[(kc * 128 + mw + mt * 16 + ln) * 8];
            #pragma unroll
            for (int nt = 0; nt < 2; ++nt)
                b[nt] = *(const s16x8*)&Bl[(kc * 64 + nw + nt * 16 + ln) * 8];
            #pragma unroll
            for (int mt = 0; mt < 4; ++mt)
                #pragma unroll
                for (int nt = 0; nt < 2; ++nt)
                    acc[mt][nt] = __builtin_amdgcn_mfma_f32_16x16x32_bf16(a[mt], b[nt], acc[mt][nt], 0, 0, 0);
        }
    }

    #pragma unroll
    for (int mt = 0; mt < 4; ++mt)
        #pragma unroll
        for (int nt = 0; nt < 2; ++nt)
            #pragma unroll
            for (int i = 0; i < 4; ++i) {
                const int m = m0 + mw + mt * 16 + qd * 4 + i;
                const int n = n0 + nw + nt * 16 + ln;
                outF[(size_t)m * 1024 + n] = acc[mt][nt][i];
            }
}

// Flash attention, double-buffered K/V DMA, one barrier per kt.
// Grid (16,32) = (S/128, B*H). 512 thr = 8 waves x 16 q-rows.
__global__ __launch_bounds__(512, 4)
void fattn(const unsigned short* __restrict__ Q, const unsigned short* __restrict__ Ksw,
           const unsigned short* __restrict__ Vsw, unsigned short* __restrict__ ctx) {
    __shared__ __align__(16) unsigned short Ks2[2][512 * 8];
    __shared__ __align__(16) unsigned short Vs2[2][512 * 8];
    __shared__ __align__(16) unsigned short Pw[8][16 * 72];

    const int t = threadIdx.x, lane = t & 63, w = t >> 6;
    const int ln = lane & 15, qd = lane >> 4;
    const int bh = blockIdx.y, m0 = blockIdx.x * 128;
    const size_t head = (size_t)bh * 2048 * 64;

    s16x8 qf[2];
    #pragma unroll
    for (int kk = 0; kk < 2; ++kk)
        qf[kk] = *(const s16x8*)(Q + head + (size_t)(m0 + w * 16 + ln) * 64 + kk * 32 + qd * 8);

    f32x4v accO[4] = {};
    float lsum[4] = {};
    unsigned short* pw = Pw[w];

    {   // prefetch kt=0 into buf 0 (per-lane address via lane)
        const size_t tb = (size_t)bh * 32 * 512;
        gld_lds16(Ksw + (tb + w * 64 + lane) * 8, &Ks2[0][(w * 64) * 8]);
        gld_lds16(Vsw + (tb + w * 64 + lane) * 8, &Vs2[0][(w * 64) * 8]);
    }

    for (int kt = 0; kt < 32; ++kt) {
        const int cur = kt & 1;
        __syncthreads();   // drains vmcnt(0): buf[cur] DMA complete; prior LDS reads done
        if (kt + 1 < 32) {  // prefetch kt+1 into the other buffer
            const size_t tb = ((size_t)bh * 32 + kt + 1) * 512;
            gld_lds16(Ksw + (tb + w * 64 + lane) * 8, &Ks2[cur ^ 1][(w * 64) * 8]);
            gld_lds16(Vsw + (tb + w * 64 + lane) * 8, &Vs2[cur ^ 1][(w * 64) * 8]);
        }

        // S = Q K^T (pre-scaled by log2e)
        f32x4v accS[4] = {};
        #pragma unroll
        for (int kk = 0; kk < 2; ++kk)
            #pragma unroll
            for (int nt = 0; nt < 4; ++nt) {
                s16x8 b = *(const s16x8*)&Ks2[cur][((kk * 4 + qd) * 64 + nt * 16 + ln) * 8];
                accS[nt] = __builtin_amdgcn_mfma_f32_16x16x32_bf16(qf[kk], b, accS[nt], 0, 0, 0);
            }

        // P = 2^S, row-sums, direct bf16 spill (C-layout -> A-layout)
        #pragma unroll
        for (int nt = 0; nt < 4; ++nt)
            #pragma unroll
            for (int i = 0; i < 4; ++i) {
                float p = exp2f(accS[nt][i]);
                lsum[i] += p;
                pw[(qd * 4 + i) * 72 + nt * 16 + ln] = f2bf(p);
            }

        // O += P V
        #pragma unroll
        for (int kk = 0; kk < 2; ++kk) {
            s16x8 a = *(const s16x8*)&pw[ln * 72 + kk * 32 + qd * 8];
            #pragma unroll
            for (int nt = 0; nt < 4; ++nt) {
                s16x8 b = *(const s16x8*)&Vs2[cur][((kk * 4 + qd) * 64 + nt * 16 + ln) * 8];
                accO[nt] = __builtin_amdgcn_mfma_f32_16x16x32_bf16(a, b, accO[nt], 0, 0, 0);
            }
        }
    }

    #pragma unroll
    for (int i = 0; i < 4; ++i) {
        float s = lsum[i];
        #pragma unroll
        for (int off = 1; off < 16; off <<= 1) s += __shfl_xor(s, off, 64);
        lsum[i] = 1.f / s;
    }

    // ctx in A/W swizzle: m = b*2048+s, k = h*64+d
    #pragma unroll
    for (int i = 0; i < 4; ++i) {
        const int mrow = (bh >> 4) * 2048 + m0 + w * 16 + qd * 4 + i;
        #pragma unroll
        for (int nt = 0; nt < 4; ++nt) {
            const int k = (bh & 15) * 64 + nt * 16 + ln;
            const size_t g = ((size_t)(mrow >> 7) * 128 + (k >> 3)) * 128 + (mrow & 127);
            ctx[g * 8 + (k & 7)] = f2bf(accO[nt][i] * lsum[i]);
        }
    }
}

extern "C" void kernel_launch(void* const* d_in, const int* in_sizes, int n_in,
                              void* d_out, int out_size, void* d_ws, size_t ws_size,
                              hipStream_t stream) {
    char* ws = (char*)d_ws;
    unsigned short* Qb  = (unsigned short*)(ws);
    unsigned short* Ksw = (unsigned short*)(ws + ((size_t)8 << 20));
    unsigned short* Vsw = (unsigned short*)(ws + ((size_t)16 << 20));
    unsigned short* Wqt = (unsigned short*)(ws + ((size_t)24 << 20));
    unsigned short* Wkt = (unsigned short*)(ws + ((size_t)26 << 20));
    unsigned short* Wvt = (unsigned short*)(ws + ((size_t)28 << 20));
    unsigned short* ctx = (unsigned short*)(ws + ((size_t)24 << 20));  // after QKV GEMM
    unsigned short* Wot = (unsigned short*)(ws);                        // after fattn (Qb dead)

    cvt3<<<dim3(16, 16, 3), 256, 0, stream>>>((const float*)d_in[3], (const float*)d_in[4],
                                              (const float*)d_in[5], Wqt, Wkt, Wvt);

    gemm_qkv<<<dim3(8, 32, 3), 256, 0, stream>>>(
        (const float*)d_in[0], (const float*)d_in[1], (const float*)d_in[2],
        Wqt, Wkt, Wvt, Qb, Ksw, Vsw, 0.125f * 1.44269504f);

    fattn<<<dim3(16, 32), dim3(512), 0, stream>>>(Qb, Ksw, Vsw, ctx);

    cvt3<<<dim3(16, 16, 1), 256, 0, stream>>>((const float*)d_in[6], nullptr, nullptr,
                                              Wot, nullptr, nullptr);

    gemm_out<<<dim3(16, 32), 256, 0, stream>>>(ctx, Wot, (float*)d_out);
}